// Round 8
// baseline (389.593 us; speedup 1.0000x reference)
//
#include <hip/hip_runtime.h>

typedef _Float16 f16_t;
typedef float f32x4 __attribute__((ext_vector_type(4)));
typedef _Float16 f16x8 __attribute__((ext_vector_type(8)));
typedef unsigned int u32x4 __attribute__((ext_vector_type(4)));

#define AS1 __attribute__((address_space(1)))
#define AS3 __attribute__((address_space(3)))

__device__ __forceinline__ void gload_lds16(const void* g, void* l) {
  __builtin_amdgcn_global_load_lds((const AS1 void*)g, (AS3 void*)l, 16, 0, 0);
}

// ------------- adj = softmax(relu(E E^T), axis=1), single fp16 plane -------
// Stored pre-scaled by 2^12 (fp16 denormal guard); fgemm epilogue × 2^-12.
__global__ __launch_bounds__(256) void adj_softmax(const float* __restrict__ emb,
                                                   f16_t* __restrict__ adjF) {
  __shared__ float vals[2048];
  __shared__ float red[16];
  const int n = blockIdx.x;
  const int t = threadIdx.x;
  const int lane = t & 63, wave = t >> 6;
  float en[10];
#pragma unroll
  for (int e = 0; e < 10; ++e) en[e] = emb[n * 10 + e];
  float lm = 0.0f;
  for (int m = t; m < 2048; m += 256) {
    const float* em = emb + m * 10;
    float d = 0.f;
#pragma unroll
    for (int e = 0; e < 10; ++e) d += en[e] * em[e];
    d = fmaxf(d, 0.0f);
    vals[m] = d;
    lm = fmaxf(lm, d);
  }
#pragma unroll
  for (int off = 32; off > 0; off >>= 1) lm = fmaxf(lm, __shfl_down(lm, off));
  if (lane == 0) red[wave] = lm;
  __syncthreads();
  const float gmax = fmaxf(fmaxf(red[0], red[1]), fmaxf(red[2], red[3]));
  float ls = 0.f;
  for (int m = t; m < 2048; m += 256) {
    float ev = expf(vals[m] - gmax);
    vals[m] = ev;
    ls += ev;
  }
#pragma unroll
  for (int off = 32; off > 0; off >>= 1) ls += __shfl_down(ls, off);
  if (lane == 0) red[8 + wave] = ls;
  __syncthreads();
  const float inv = 4096.0f / (red[8] + red[9] + red[10] + red[11]);
  for (int m = t; m < 2048; m += 256) {
    adjF[(long)n * 2048 + m] = (f16_t)(vals[m] * inv);
  }
}

// ------------- XT[b*64+i][m] = x[b][m][i], single fp16 plane ---------------
__global__ __launch_bounds__(256) void split_xt(const float* __restrict__ x,
                                                f16_t* __restrict__ XTh) {
  __shared__ float tile[64][65];
  const int m0 = blockIdx.x * 64;
  const int b = blockIdx.y;
  const int tx = threadIdx.x & 63, ty = threadIdx.x >> 6;
  for (int r = ty; r < 64; r += 4)
    tile[r][tx] = x[(long)b * 131072 + (long)(m0 + r) * 64 + tx];
  __syncthreads();
  for (int r = ty; r < 64; r += 4) {
    long idx = (long)(b * 64 + r) * 2048 + m0 + tx;
    XTh[idx] = (f16_t)tile[tx][r];
  }
}

// ------------- fp16 transpose: out[c][r] = in[r][c] (fp32 LDS tile) --------
__global__ __launch_bounds__(256) void tsplit(const f16_t* __restrict__ in,
                                              f16_t* __restrict__ oH, int R, int C) {
  __shared__ float tile[64][65];
  const int c0 = blockIdx.x * 64, r0 = blockIdx.y * 64;
  const int tx = threadIdx.x & 63, ty = threadIdx.x >> 6;
  for (int r = ty; r < 64; r += 4)
    tile[r][tx] = (float)in[(long)(r0 + r) * C + c0 + tx];
  __syncthreads();
  for (int r = ty; r < 64; r += 4) {
    long idx = (long)(c0 + r) * R + r0 + tx;
    oH[idx] = (f16_t)tile[tx][r];
  }
}

// ------------- permute w_pool (E,3,I,O) -> P[e][o*KI + k*I+i], fp32 --------
__global__ __launch_bounds__(256) void permute_pool(const float* __restrict__ wp,
                                                    float* __restrict__ P,
                                                    int KI, int I, int O) {
  const int g = blockIdx.x * 256 + threadIdx.x;
  const int per = KI * O;  // 24576
  const int e = g / per, rem = g % per;
  const int o = rem / KI, kk = rem % KI;
  const int k = kk / I, i = kk % I;
  P[g] = wp[(long)((e * 3 + k) * I + i) * O + o];
}

// ------------- W[n][c] = fp16(sum_e emb[n,e] * P[e][c]) — 96 MiB out -------
// v3: c-tile 2048, 16B nontemporal stores (W is never L2-reused; stream it),
// 20 float4 P-loads hoisted to registers reused across 16 nodes.
__global__ __launch_bounds__(256) void wgen(const float* __restrict__ P,
                                            const float* __restrict__ emb,
                                            f16_t* __restrict__ W) {
  __shared__ float es[160];
  const int c0 = blockIdx.x * 2048;
  const int n0 = blockIdx.y * 16;
  const int t = threadIdx.x;
  const int i8 = t * 8;
  if (t < 160) es[t] = emb[n0 * 10 + t];
  float4 pa[10], pb[10];
#pragma unroll
  for (int e = 0; e < 10; ++e) {
    pa[e] = *(const float4*)(P + (long)e * 24576 + c0 + i8);
    pb[e] = *(const float4*)(P + (long)e * 24576 + c0 + i8 + 4);
  }
  __syncthreads();
#pragma unroll 2
  for (int nn = 0; nn < 16; ++nn) {
    const float* ep = es + nn * 10;
    float v[8] = {0.f, 0.f, 0.f, 0.f, 0.f, 0.f, 0.f, 0.f};
#pragma unroll
    for (int e = 0; e < 10; ++e) {
      const float ee = ep[e];
      v[0] += ee * pa[e].x; v[1] += ee * pa[e].y;
      v[2] += ee * pa[e].z; v[3] += ee * pa[e].w;
      v[4] += ee * pb[e].x; v[5] += ee * pb[e].y;
      v[6] += ee * pb[e].z; v[7] += ee * pb[e].w;
    }
    union { u32x4 u; f16_t h[8]; } o;
#pragma unroll
    for (int q = 0; q < 8; ++q) o.h[q] = (f16_t)v[q];
    __builtin_nontemporal_store(o.u, (u32x4*)(W + (long)(n0 + nn) * 24576 + c0 + i8));
  }
}

// ------------- unified fused GEMM (fp16), single-plane, fp16 C -------------
// R1-proven structure (128Mx64N, 4 waves of 32Mx64N, BK=64, XOR-swizzled
// LDS, single-buffered 2-barrier loop, 2 blocks/CU).  C emitted as fp16
// (consumers convert to fp16 anyway — halves C traffic).
// WT: also emit transposed fp16 C (next GEMM's B operand).
template <int WT>
__global__ __launch_bounds__(256) void fgemm(const f16_t* __restrict__ A,
                                             const f16_t* __restrict__ B,
                                             f16_t* __restrict__ Ch,
                                             f16_t* __restrict__ Th,
                                             int K, int ldc) {
  __shared__ __align__(16) f16_t Ash[128 * 64];
  __shared__ __align__(16) f16_t Bsh[64 * 64];
  const int t = threadIdx.x;
  const int wave = t >> 6, lane = t & 63;
  const long m0 = (long)blockIdx.y * 128;
  const long n0 = (long)blockIdx.x * 64;
  const int srow = t >> 3;
  const int sc8 = ((t & 7) ^ (srow & 7)) << 3;
  const int fr = lane & 15;
  const int quad = lane >> 4;
  const int wm = wave * 32;
  char* lA = (char*)Ash + wave * 1024;
  char* lB = (char*)Bsh + wave * 1024;
  f32x4 acc[2][4] = {};
  for (int k0 = 0; k0 < K; k0 += 64) {
#pragma unroll
    for (int q = 0; q < 4; ++q)
      gload_lds16(A + (m0 + q * 32 + srow) * K + k0 + sc8, lA + q * 4096);
#pragma unroll
    for (int q = 0; q < 2; ++q)
      gload_lds16(B + (n0 + q * 32 + srow) * K + k0 + sc8, lB + q * 4096);
    __syncthreads();
#pragma unroll
    for (int kh = 0; kh < 2; ++kh) {
      const int cbase = kh * 4 + quad;
      f16x8 ah[2], bh[4];
#pragma unroll
      for (int i = 0; i < 2; ++i) {
        const int r = wm + i * 16 + fr;
        ah[i] = *(const f16x8*)(Ash + r * 64 + ((cbase ^ (fr & 7)) << 3));
      }
#pragma unroll
      for (int j = 0; j < 4; ++j) {
        const int r = j * 16 + fr;
        bh[j] = *(const f16x8*)(Bsh + r * 64 + ((cbase ^ (fr & 7)) << 3));
      }
#pragma unroll
      for (int i = 0; i < 2; ++i)
#pragma unroll
        for (int j = 0; j < 4; ++j)
          acc[i][j] = __builtin_amdgcn_mfma_f32_16x16x32_f16(ah[i], bh[j], acc[i][j], 0, 0, 0);
    }
    __syncthreads();
  }
  const int crow = quad * 4, ccol = fr;
#pragma unroll
  for (int i = 0; i < 2; ++i)
#pragma unroll
    for (int j = 0; j < 4; ++j) {
      f16_t v[4];
#pragma unroll
      for (int r = 0; r < 4; ++r) v[r] = (f16_t)(acc[i][j][r] * 0.000244140625f);
      const long gmb = m0 + wm + i * 16 + crow;
      const long gn = n0 + j * 16 + ccol;
#pragma unroll
      for (int r = 0; r < 4; ++r) Ch[(gmb + r) * ldc + gn] = v[r];
      if (WT) {
        union { ushort4 u; f16_t h[4]; } ph;
#pragma unroll
        for (int r = 0; r < 4; ++r) ph.h[r] = v[r];
        *(ushort4*)(Th + gn * 2048 + gmb) = ph.u;
      }
    }
}

// ------------- gate: one block per node n (grid 2048) ----------------------
// fp16 inputs (Xg1h/Xg2h), fp16 Z output.
__global__ __launch_bounds__(256) void gate_kernel(
    const float* __restrict__ x, const f16_t* __restrict__ Xg1h,
    const f16_t* __restrict__ Xg2h, const f16_t* __restrict__ Wg,
    const float* __restrict__ bpool, const float* __restrict__ emb,
    f16_t* __restrict__ Zh, f16_t* __restrict__ rb) {
  __shared__ __align__(16) f16_t Ahi[32 * 200];
  const int n = blockIdx.x;
  const int t = threadIdx.x;
  float en[10];
#pragma unroll
  for (int e = 0; e < 10; ++e) en[e] = emb[n * 10 + e];
  {
    const int b = t >> 3, i8 = (t & 7) * 8;
    const float* s0 = x + (long)b * 131072 + (long)n * 64 + i8;
    f16x8 l1 = *(const f16x8*)(Xg1h + (long)n * 2048 + b * 64 + i8);
    f16x8 l2 = *(const f16x8*)(Xg2h + (long)n * 2048 + b * 64 + i8);
    float v0[8];
#pragma unroll
    for (int j = 0; j < 8; ++j) v0[j] = s0[j];
    union { uint4 u; f16_t h[8]; } th;
#pragma unroll
    for (int j = 0; j < 8; ++j) th.h[j] = (f16_t)v0[j];
    *(uint4*)(Ahi + b * 200 + i8) = th.u;
#pragma unroll
    for (int j = 0; j < 8; ++j) th.h[j] = l1[j];
    *(uint4*)(Ahi + b * 200 + 64 + i8) = th.u;
#pragma unroll
    for (int j = 0; j < 8; ++j) th.h[j] = (f16_t)(2.0f * (float)l2[j] - v0[j]);
    *(uint4*)(Ahi + b * 200 + 128 + i8) = th.u;
  }
  __syncthreads();
  const int wave = t >> 6, lane = t & 63;
  const int ob = wave * 32;
  const int fr = lane & 15, qk = (lane >> 4) * 8;
  const f16_t* Wp0 = Wg + (long)n * 24576 + (ob + fr) * 192 + qk;
  const f16_t* Wp1 = Wp0 + 16 * 192;
  f32x4 acc[2][2] = {};
#pragma unroll
  for (int k0 = 0; k0 < 192; k0 += 32) {
    f16x8 b0 = *(const f16x8*)(Wp0 + k0);
    f16x8 b1 = *(const f16x8*)(Wp1 + k0);
    f16x8 a0 = *(const f16x8*)(Ahi + fr * 200 + k0 + qk);
    f16x8 a1 = *(const f16x8*)(Ahi + (16 + fr) * 200 + k0 + qk);
    acc[0][0] = __builtin_amdgcn_mfma_f32_16x16x32_f16(a0, b0, acc[0][0], 0, 0, 0);
    acc[1][0] = __builtin_amdgcn_mfma_f32_16x16x32_f16(a1, b0, acc[1][0], 0, 0, 0);
    acc[0][1] = __builtin_amdgcn_mfma_f32_16x16x32_f16(a0, b1, acc[0][1], 0, 0, 0);
    acc[1][1] = __builtin_amdgcn_mfma_f32_16x16x32_f16(a1, b1, acc[1][1], 0, 0, 0);
  }
  const int quad = lane >> 4;
#pragma unroll
  for (int j = 0; j < 2; ++j) {
    const int o = ob + j * 16 + fr;   // 0..127
    float bias = 0.f;
#pragma unroll
    for (int e = 0; e < 10; ++e) bias += en[e] * bpool[e * 128 + o];
#pragma unroll
    for (int i2 = 0; i2 < 2; ++i2)
#pragma unroll
      for (int r = 0; r < 4; ++r) {
        const int b = i2 * 16 + quad * 4 + r;
        float v = acc[i2][j][r] + bias;
        v = 1.0f / (1.0f + expf(-v));
        if (o < 64)
          Zh[(long)n * 2048 + b * 64 + o] = (f16_t)v;
        else
          rb[(long)n * 2048 + b * 64 + (o - 64)] = (f16_t)v;
      }
  }
}

// ------------- update: one block per node n (grid 2048) --------------------
// fp16 inputs (Zh/Xg1h/Cgz1h/Xg2h/Cgz2h).
__global__ __launch_bounds__(256) void update_kernel(
    const float* __restrict__ x, const f16_t* __restrict__ Zh,
    const f16_t* __restrict__ Xg1h, const f16_t* __restrict__ Cgz1h,
    const f16_t* __restrict__ Xg2h, const f16_t* __restrict__ Cgz2h,
    const f16_t* __restrict__ Wu, const float* __restrict__ bpool,
    const float* __restrict__ emb, const f16_t* __restrict__ rb,
    float* __restrict__ out) {
  __shared__ __align__(16) f16_t Ahi[32 * 392];
  const int n = blockIdx.x;
  const int t = threadIdx.x;
  float en[10];
#pragma unroll
  for (int e = 0; e < 10; ++e) en[e] = emb[n * 10 + e];
#pragma unroll
  for (int r = 0; r < 2; ++r) {
    const int c = r * 2048 + t * 8;  // (b, j) over 32 x 128
    const int b = c >> 7, j = c & 127;
    const int lo64 = j & 63;
    float v0[8];
    if (j < 64) {
      const float* s0 = x + (long)b * 131072 + (long)n * 64 + lo64;
#pragma unroll
      for (int q = 0; q < 8; ++q) v0[q] = s0[q];
    } else {
      f16x8 l0 = *(const f16x8*)(Zh + (long)n * 2048 + b * 64 + lo64);
#pragma unroll
      for (int q = 0; q < 8; ++q) v0[q] = (float)l0[q];
    }
    const f16_t* s1 = (j < 64) ? (Xg1h + (long)n * 2048 + b * 64 + lo64)
                               : (Cgz1h + (long)n * 2048 + b * 64 + lo64);
    const f16_t* s2 = (j < 64) ? (Xg2h + (long)n * 2048 + b * 64 + lo64)
                               : (Cgz2h + (long)n * 2048 + b * 64 + lo64);
    f16x8 l1 = *(const f16x8*)s1;
    f16x8 l2 = *(const f16x8*)s2;
    union { uint4 u; f16_t h[8]; } th;
#pragma unroll
    for (int q = 0; q < 8; ++q) th.h[q] = (f16_t)v0[q];
    *(uint4*)(Ahi + b * 392 + j) = th.u;
#pragma unroll
    for (int q = 0; q < 8; ++q) th.h[q] = l1[q];
    *(uint4*)(Ahi + b * 392 + 128 + j) = th.u;
#pragma unroll
    for (int q = 0; q < 8; ++q) th.h[q] = (f16_t)(2.0f * (float)l2[q] - v0[q]);
    *(uint4*)(Ahi + b * 392 + 256 + j) = th.u;
  }
  __syncthreads();
  const int wave = t >> 6, lane = t & 63;
  const int ob = wave * 16;            // 64 o across 4 waves
  const int fr = lane & 15, qk = (lane >> 4) * 8;
  const f16_t* Wp = Wu + (long)n * 24576 + (ob + fr) * 384 + qk;
  f32x4 acc[2] = {};
#pragma unroll
  for (int k0 = 0; k0 < 384; k0 += 32) {
    f16x8 bhv = *(const f16x8*)(Wp + k0);
    f16x8 a0 = *(const f16x8*)(Ahi + fr * 392 + k0 + qk);
    f16x8 a1 = *(const f16x8*)(Ahi + (16 + fr) * 392 + k0 + qk);
    acc[0] = __builtin_amdgcn_mfma_f32_16x16x32_f16(a0, bhv, acc[0], 0, 0, 0);
    acc[1] = __builtin_amdgcn_mfma_f32_16x16x32_f16(a1, bhv, acc[1], 0, 0, 0);
  }
  const int quad = lane >> 4;
  const int og = ob + fr;
  float bias = 0.f;
#pragma unroll
  for (int e = 0; e < 10; ++e) bias += en[e] * bpool[e * 64 + og];
#pragma unroll
  for (int i2 = 0; i2 < 2; ++i2)
#pragma unroll
    for (int r = 0; r < 4; ++r) {
      const int b = i2 * 16 + quad * 4 + r;
      float hc = tanhf(acc[i2][r] + bias);
      float rr = (float)rb[(long)n * 2048 + b * 64 + og];
      float xv = x[(long)b * 131072 + (long)n * 64 + og];
      out[(long)b * 131072 + (long)n * 64 + og] = rr * xv + (1.0f - rr) * hc;
    }
}

extern "C" void kernel_launch(void* const* d_in, const int* in_sizes, int n_in,
                              void* d_out, int out_size, void* d_ws, size_t ws_size,
                              hipStream_t stream) {
  (void)in_sizes; (void)n_in; (void)out_size;
  const float* x   = (const float*)d_in[0];
  const float* emb = (const float*)d_in[2];
  const float* gwp = (const float*)d_in[3];
  const float* gbp = (const float*)d_in[4];
  const float* uwp = (const float*)d_in[5];
  const float* ubp = (const float*)d_in[6];
  float* out = (float*)d_out;
  char* ws = (char*)d_ws;

  // high-water now 169,738,240 B; keep prior guard (known-satisfied).
  if (ws_size < 169738240ull) return;

  // Phases: P0 setup | P1 G1,G2 | P2 gate | P3 tsplit,G3,G4 | P4 wgen(Wu),update
  f16_t*  Xg1h  = (f16_t*)(ws);                  //  8 MiB  (P1..P4)
  f16_t*  Xg2h  = (f16_t*)(ws + 8388608);        //  8 MiB  (P1..P4)
  f16_t*  Zh    = (f16_t*)(ws + 16777216);       //  8 MiB  (P2..P4)
  f16_t*  T1h   = (f16_t*)(ws + 16777216);       //  8 MiB overlay (P1 only: G1->G2)
  f16_t*  rb    = (f16_t*)(ws + 25165824);       //  8 MiB  (P2..P4)
  float*  Pg    = (float*)(ws + 33554432);       // 983040
  float*  Pu    = (float*)(ws + 34537472);       // 983040 (ends 35520512)
  f16_t*  adjF  = (f16_t*)(ws + 35520512);       //  8 MiB  (P0..P3)
  f16_t*  Sh    = (f16_t*)(ws + 43909120);       //  8 MiB  (P1, P3)
  f16_t*  Wg    = (f16_t*)(ws + 52297728);       // 96 MiB  (dead post-gate; ends 152961024)
  f16_t*  T2h   = (f16_t*)(ws + 52297728);       //  8 MiB overlay Wg head (P3)
  f16_t*  Wu    = (f16_t*)(ws + 52297728);       // 96 MiB overlay (P4)
  f16_t*  Cgz1h = (f16_t*)(ws + 152961024);      //  8 MiB  (P3..P4)
  f16_t*  Cgz2h = (f16_t*)(ws + 161349632);      //  8 MiB  (ends 169738240)

  permute_pool<<<960, 256, 0, stream>>>(gwp, Pg, 192, 64, 128);
  permute_pool<<<960, 256, 0, stream>>>(uwp, Pu, 384, 128, 64);
  wgen<<<dim3(12, 128), 256, 0, stream>>>(Pg, emb, Wg);
  adj_softmax<<<2048, 256, 0, stream>>>(emb, adjF);
  split_xt<<<dim3(32, 32), 256, 0, stream>>>(x, Sh);

  // G1: Xg1 = adj @ X     (+ fused transposed fp16 C -> T1)
  fgemm<1><<<dim3(32, 16), 256, 0, stream>>>(adjF, Sh, Xg1h, T1h, 2048, 2048);
  // G2: Xg2 = adj @ Xg1
  fgemm<0><<<dim3(32, 16), 256, 0, stream>>>(adjF, T1h, Xg2h, nullptr, 2048, 2048);

  gate_kernel<<<2048, 256, 0, stream>>>(x, Xg1h, Xg2h, Wg, gbp, emb, Zh, rb);

  tsplit<<<dim3(32, 32), 256, 0, stream>>>(Zh, Sh, 2048, 2048);
  // G3: Cgz1 = adj @ Z    (+ fused transposed fp16 C -> T2, in dead-Wg space)
  fgemm<1><<<dim3(32, 16), 256, 0, stream>>>(adjF, Sh, Cgz1h, T2h, 2048, 2048);
  // G4: Cgz2 = adj @ Cgz1
  fgemm<0><<<dim3(32, 16), 256, 0, stream>>>(adjF, T2h, Cgz2h, nullptr, 2048, 2048);

  wgen<<<dim3(12, 128), 256, 0, stream>>>(Pu, emb, Wu);
  update_kernel<<<2048, 256, 0, stream>>>(x, Zh, Xg1h, Cgz1h, Xg2h, Cgz2h, Wu,
                                          ubp, emb, rb, out);
}

// Round 9
// 331.796 us; speedup vs baseline: 1.1742x; 1.1742x over previous
//
#include <hip/hip_runtime.h>

typedef _Float16 f16_t;
typedef float f32x4 __attribute__((ext_vector_type(4)));
typedef _Float16 f16x8 __attribute__((ext_vector_type(8)));
typedef unsigned int u32x4 __attribute__((ext_vector_type(4)));

#define AS1 __attribute__((address_space(1)))
#define AS3 __attribute__((address_space(3)))

__device__ __forceinline__ void gload_lds16(const void* g, void* l) {
  __builtin_amdgcn_global_load_lds((const AS1 void*)g, (AS3 void*)l, 16, 0, 0);
}

// ------------- adj = softmax(relu(E E^T), axis=1), single fp16 plane -------
// Stored pre-scaled by 2^12 (fp16 denormal guard); fgemm epilogue × 2^-12.
__global__ __launch_bounds__(256) void adj_softmax(const float* __restrict__ emb,
                                                   f16_t* __restrict__ adjF) {
  __shared__ float vals[2048];
  __shared__ float red[16];
  const int n = blockIdx.x;
  const int t = threadIdx.x;
  const int lane = t & 63, wave = t >> 6;
  float en[10];
#pragma unroll
  for (int e = 0; e < 10; ++e) en[e] = emb[n * 10 + e];
  float lm = 0.0f;
  for (int m = t; m < 2048; m += 256) {
    const float* em = emb + m * 10;
    float d = 0.f;
#pragma unroll
    for (int e = 0; e < 10; ++e) d += en[e] * em[e];
    d = fmaxf(d, 0.0f);
    vals[m] = d;
    lm = fmaxf(lm, d);
  }
#pragma unroll
  for (int off = 32; off > 0; off >>= 1) lm = fmaxf(lm, __shfl_down(lm, off));
  if (lane == 0) red[wave] = lm;
  __syncthreads();
  const float gmax = fmaxf(fmaxf(red[0], red[1]), fmaxf(red[2], red[3]));
  float ls = 0.f;
  for (int m = t; m < 2048; m += 256) {
    float ev = expf(vals[m] - gmax);
    vals[m] = ev;
    ls += ev;
  }
#pragma unroll
  for (int off = 32; off > 0; off >>= 1) ls += __shfl_down(ls, off);
  if (lane == 0) red[8 + wave] = ls;
  __syncthreads();
  const float inv = 4096.0f / (red[8] + red[9] + red[10] + red[11]);
  for (int m = t; m < 2048; m += 256) {
    adjF[(long)n * 2048 + m] = (f16_t)(vals[m] * inv);
  }
}

// ------------- XT[b*64+i][m] = x[b][m][i], single fp16 plane ---------------
__global__ __launch_bounds__(256) void split_xt(const float* __restrict__ x,
                                                f16_t* __restrict__ XTh) {
  __shared__ float tile[64][65];
  const int m0 = blockIdx.x * 64;
  const int b = blockIdx.y;
  const int tx = threadIdx.x & 63, ty = threadIdx.x >> 6;
  for (int r = ty; r < 64; r += 4)
    tile[r][tx] = x[(long)b * 131072 + (long)(m0 + r) * 64 + tx];
  __syncthreads();
  for (int r = ty; r < 64; r += 4) {
    long idx = (long)(b * 64 + r) * 2048 + m0 + tx;
    XTh[idx] = (f16_t)tile[tx][r];
  }
}

// ------------- fp16 transpose: out[c][r] = in[r][c] (fp32 LDS tile) --------
__global__ __launch_bounds__(256) void tsplit(const f16_t* __restrict__ in,
                                              f16_t* __restrict__ oH, int R, int C) {
  __shared__ float tile[64][65];
  const int c0 = blockIdx.x * 64, r0 = blockIdx.y * 64;
  const int tx = threadIdx.x & 63, ty = threadIdx.x >> 6;
  for (int r = ty; r < 64; r += 4)
    tile[r][tx] = (float)in[(long)(r0 + r) * C + c0 + tx];
  __syncthreads();
  for (int r = ty; r < 64; r += 4) {
    long idx = (long)(c0 + r) * R + r0 + tx;
    oH[idx] = (f16_t)tile[tx][r];
  }
}

// ------------- permute w_pool (E,3,I,O) -> P[e][o*KI + k*I+i], fp32 --------
__global__ __launch_bounds__(256) void permute_pool(const float* __restrict__ wp,
                                                    float* __restrict__ P,
                                                    int KI, int I, int O) {
  const int g = blockIdx.x * 256 + threadIdx.x;
  const int per = KI * O;  // 24576
  const int e = g / per, rem = g % per;
  const int o = rem / KI, kk = rem % KI;
  const int k = kk / I, i = kk % I;
  P[g] = wp[(long)((e * 3 + k) * I + i) * O + o];
}

// ------------- W[n][c] = fp16(sum_e emb[n,e] * P[e][c]) — 96 MiB out -------
// c-tile 2048, 16B PLAIN stores (round-8 post-mortem: nontemporal bypassed
// L3 and forced gate/update to re-fetch all 96 MiB from DRAM — W fits L3,
// let it allocate), 20 float4 P-loads hoisted to registers.
__global__ __launch_bounds__(256) void wgen(const float* __restrict__ P,
                                            const float* __restrict__ emb,
                                            f16_t* __restrict__ W) {
  __shared__ float es[160];
  const int c0 = blockIdx.x * 2048;
  const int n0 = blockIdx.y * 16;
  const int t = threadIdx.x;
  const int i8 = t * 8;
  if (t < 160) es[t] = emb[n0 * 10 + t];
  float4 pa[10], pb[10];
#pragma unroll
  for (int e = 0; e < 10; ++e) {
    pa[e] = *(const float4*)(P + (long)e * 24576 + c0 + i8);
    pb[e] = *(const float4*)(P + (long)e * 24576 + c0 + i8 + 4);
  }
  __syncthreads();
#pragma unroll 2
  for (int nn = 0; nn < 16; ++nn) {
    const float* ep = es + nn * 10;
    float v[8] = {0.f, 0.f, 0.f, 0.f, 0.f, 0.f, 0.f, 0.f};
#pragma unroll
    for (int e = 0; e < 10; ++e) {
      const float ee = ep[e];
      v[0] += ee * pa[e].x; v[1] += ee * pa[e].y;
      v[2] += ee * pa[e].z; v[3] += ee * pa[e].w;
      v[4] += ee * pb[e].x; v[5] += ee * pb[e].y;
      v[6] += ee * pb[e].z; v[7] += ee * pb[e].w;
    }
    union { u32x4 u; f16_t h[8]; } o;
#pragma unroll
    for (int q = 0; q < 8; ++q) o.h[q] = (f16_t)v[q];
    *(u32x4*)(W + (long)(n0 + nn) * 24576 + c0 + i8) = o.u;
  }
}

// ------------- unified fused GEMM (fp16), single-plane, fp16 C -------------
// R1-proven structure (128Mx64N, 4 waves of 32Mx64N, BK=64, XOR-swizzled
// LDS, single-buffered 2-barrier loop, 2 blocks/CU).
// WT: also emit transposed fp16 C (next GEMM's B operand).
template <int WT>
__global__ __launch_bounds__(256) void fgemm(const f16_t* __restrict__ A,
                                             const f16_t* __restrict__ B,
                                             f16_t* __restrict__ Ch,
                                             f16_t* __restrict__ Th,
                                             int K, int ldc) {
  __shared__ __align__(16) f16_t Ash[128 * 64];
  __shared__ __align__(16) f16_t Bsh[64 * 64];
  const int t = threadIdx.x;
  const int wave = t >> 6, lane = t & 63;
  const long m0 = (long)blockIdx.y * 128;
  const long n0 = (long)blockIdx.x * 64;
  const int srow = t >> 3;
  const int sc8 = ((t & 7) ^ (srow & 7)) << 3;
  const int fr = lane & 15;
  const int quad = lane >> 4;
  const int wm = wave * 32;
  char* lA = (char*)Ash + wave * 1024;
  char* lB = (char*)Bsh + wave * 1024;
  f32x4 acc[2][4] = {};
  for (int k0 = 0; k0 < K; k0 += 64) {
#pragma unroll
    for (int q = 0; q < 4; ++q)
      gload_lds16(A + (m0 + q * 32 + srow) * K + k0 + sc8, lA + q * 4096);
#pragma unroll
    for (int q = 0; q < 2; ++q)
      gload_lds16(B + (n0 + q * 32 + srow) * K + k0 + sc8, lB + q * 4096);
    __syncthreads();
#pragma unroll
    for (int kh = 0; kh < 2; ++kh) {
      const int cbase = kh * 4 + quad;
      f16x8 ah[2], bh[4];
#pragma unroll
      for (int i = 0; i < 2; ++i) {
        const int r = wm + i * 16 + fr;
        ah[i] = *(const f16x8*)(Ash + r * 64 + ((cbase ^ (fr & 7)) << 3));
      }
#pragma unroll
      for (int j = 0; j < 4; ++j) {
        const int r = j * 16 + fr;
        bh[j] = *(const f16x8*)(Bsh + r * 64 + ((cbase ^ (fr & 7)) << 3));
      }
#pragma unroll
      for (int i = 0; i < 2; ++i)
#pragma unroll
        for (int j = 0; j < 4; ++j)
          acc[i][j] = __builtin_amdgcn_mfma_f32_16x16x32_f16(ah[i], bh[j], acc[i][j], 0, 0, 0);
    }
    __syncthreads();
  }
  const int crow = quad * 4, ccol = fr;
#pragma unroll
  for (int i = 0; i < 2; ++i)
#pragma unroll
    for (int j = 0; j < 4; ++j) {
      f16_t v[4];
#pragma unroll
      for (int r = 0; r < 4; ++r) v[r] = (f16_t)(acc[i][j][r] * 0.000244140625f);
      const long gmb = m0 + wm + i * 16 + crow;
      const long gn = n0 + j * 16 + ccol;
#pragma unroll
      for (int r = 0; r < 4; ++r) Ch[(gmb + r) * ldc + gn] = v[r];
      if (WT) {
        union { ushort4 u; f16_t h[4]; } ph;
#pragma unroll
        for (int r = 0; r < 4; ++r) ph.h[r] = v[r];
        *(ushort4*)(Th + gn * 2048 + gmb) = ph.u;
      }
    }
}

// ------------- gate: one block per node n (grid 2048) ----------------------
// W fragments (12 x 16B/lane) preloaded to VGPRs at entry: HBM latency
// overlaps the A-staging + barrier, and the issue window is 12-deep
// (round-8 post-mortem: in-loop loads at VGPR=40 left W streaming at 39%
// of achievable BW).
__global__ __launch_bounds__(256) void gate_kernel(
    const float* __restrict__ x, const f16_t* __restrict__ Xg1h,
    const f16_t* __restrict__ Xg2h, const f16_t* __restrict__ Wg,
    const float* __restrict__ bpool, const float* __restrict__ emb,
    f16_t* __restrict__ Zh, f16_t* __restrict__ rb) {
  __shared__ __align__(16) f16_t Ahi[32 * 200];
  const int n = blockIdx.x;
  const int t = threadIdx.x;
  const int wave = t >> 6, lane = t & 63;
  const int ob = wave * 32;
  const int fr = lane & 15, qk = (lane >> 4) * 8;
  const f16_t* Wp0 = Wg + (long)n * 24576 + (ob + fr) * 192 + qk;
  const f16_t* Wp1 = Wp0 + 16 * 192;
  f16x8 w0[6], w1[6];
#pragma unroll
  for (int s = 0; s < 6; ++s) {
    w0[s] = *(const f16x8*)(Wp0 + s * 32);
    w1[s] = *(const f16x8*)(Wp1 + s * 32);
  }
  float en[10];
#pragma unroll
  for (int e = 0; e < 10; ++e) en[e] = emb[n * 10 + e];
  {
    const int b = t >> 3, i8 = (t & 7) * 8;
    const float* s0 = x + (long)b * 131072 + (long)n * 64 + i8;
    f16x8 l1 = *(const f16x8*)(Xg1h + (long)n * 2048 + b * 64 + i8);
    f16x8 l2 = *(const f16x8*)(Xg2h + (long)n * 2048 + b * 64 + i8);
    float v0[8];
#pragma unroll
    for (int j = 0; j < 8; ++j) v0[j] = s0[j];
    union { uint4 u; f16_t h[8]; } th;
#pragma unroll
    for (int j = 0; j < 8; ++j) th.h[j] = (f16_t)v0[j];
    *(uint4*)(Ahi + b * 200 + i8) = th.u;
#pragma unroll
    for (int j = 0; j < 8; ++j) th.h[j] = l1[j];
    *(uint4*)(Ahi + b * 200 + 64 + i8) = th.u;
#pragma unroll
    for (int j = 0; j < 8; ++j) th.h[j] = (f16_t)(2.0f * (float)l2[j] - v0[j]);
    *(uint4*)(Ahi + b * 200 + 128 + i8) = th.u;
  }
  __syncthreads();
  f32x4 acc[2][2] = {};
#pragma unroll
  for (int s = 0; s < 6; ++s) {
    const int k0 = s * 32;
    f16x8 a0 = *(const f16x8*)(Ahi + fr * 200 + k0 + qk);
    f16x8 a1 = *(const f16x8*)(Ahi + (16 + fr) * 200 + k0 + qk);
    acc[0][0] = __builtin_amdgcn_mfma_f32_16x16x32_f16(a0, w0[s], acc[0][0], 0, 0, 0);
    acc[1][0] = __builtin_amdgcn_mfma_f32_16x16x32_f16(a1, w0[s], acc[1][0], 0, 0, 0);
    acc[0][1] = __builtin_amdgcn_mfma_f32_16x16x32_f16(a0, w1[s], acc[0][1], 0, 0, 0);
    acc[1][1] = __builtin_amdgcn_mfma_f32_16x16x32_f16(a1, w1[s], acc[1][1], 0, 0, 0);
  }
  const int quad = lane >> 4;
#pragma unroll
  for (int j = 0; j < 2; ++j) {
    const int o = ob + j * 16 + fr;   // 0..127
    float bias = 0.f;
#pragma unroll
    for (int e = 0; e < 10; ++e) bias += en[e] * bpool[e * 128 + o];
#pragma unroll
    for (int i2 = 0; i2 < 2; ++i2)
#pragma unroll
      for (int r = 0; r < 4; ++r) {
        const int b = i2 * 16 + quad * 4 + r;
        float v = acc[i2][j][r] + bias;
        v = 1.0f / (1.0f + expf(-v));
        if (o < 64)
          Zh[(long)n * 2048 + b * 64 + o] = (f16_t)v;
        else
          rb[(long)n * 2048 + b * 64 + (o - 64)] = (f16_t)v;
      }
  }
}

// ------------- update: one block per node n (grid 2048) --------------------
// W fragments (12 x 16B/lane) preloaded to VGPRs at entry (see gate note).
__global__ __launch_bounds__(256) void update_kernel(
    const float* __restrict__ x, const f16_t* __restrict__ Zh,
    const f16_t* __restrict__ Xg1h, const f16_t* __restrict__ Cgz1h,
    const f16_t* __restrict__ Xg2h, const f16_t* __restrict__ Cgz2h,
    const f16_t* __restrict__ Wu, const float* __restrict__ bpool,
    const float* __restrict__ emb, const f16_t* __restrict__ rb,
    float* __restrict__ out) {
  __shared__ __align__(16) f16_t Ahi[32 * 392];
  const int n = blockIdx.x;
  const int t = threadIdx.x;
  const int wave = t >> 6, lane = t & 63;
  const int ob = wave * 16;            // 64 o across 4 waves
  const int fr = lane & 15, qk = (lane >> 4) * 8;
  const f16_t* Wp = Wu + (long)n * 24576 + (ob + fr) * 384 + qk;
  f16x8 wf[12];
#pragma unroll
  for (int s = 0; s < 12; ++s) wf[s] = *(const f16x8*)(Wp + s * 32);
  float en[10];
#pragma unroll
  for (int e = 0; e < 10; ++e) en[e] = emb[n * 10 + e];
#pragma unroll
  for (int r = 0; r < 2; ++r) {
    const int c = r * 2048 + t * 8;  // (b, j) over 32 x 128
    const int b = c >> 7, j = c & 127;
    const int lo64 = j & 63;
    float v0[8];
    if (j < 64) {
      const float* s0 = x + (long)b * 131072 + (long)n * 64 + lo64;
#pragma unroll
      for (int q = 0; q < 8; ++q) v0[q] = s0[q];
    } else {
      f16x8 l0 = *(const f16x8*)(Zh + (long)n * 2048 + b * 64 + lo64);
#pragma unroll
      for (int q = 0; q < 8; ++q) v0[q] = (float)l0[q];
    }
    const f16_t* s1 = (j < 64) ? (Xg1h + (long)n * 2048 + b * 64 + lo64)
                               : (Cgz1h + (long)n * 2048 + b * 64 + lo64);
    const f16_t* s2 = (j < 64) ? (Xg2h + (long)n * 2048 + b * 64 + lo64)
                               : (Cgz2h + (long)n * 2048 + b * 64 + lo64);
    f16x8 l1 = *(const f16x8*)s1;
    f16x8 l2 = *(const f16x8*)s2;
    union { uint4 u; f16_t h[8]; } th;
#pragma unroll
    for (int q = 0; q < 8; ++q) th.h[q] = (f16_t)v0[q];
    *(uint4*)(Ahi + b * 392 + j) = th.u;
#pragma unroll
    for (int q = 0; q < 8; ++q) th.h[q] = l1[q];
    *(uint4*)(Ahi + b * 392 + 128 + j) = th.u;
#pragma unroll
    for (int q = 0; q < 8; ++q) th.h[q] = (f16_t)(2.0f * (float)l2[q] - v0[q]);
    *(uint4*)(Ahi + b * 392 + 256 + j) = th.u;
  }
  __syncthreads();
  f32x4 acc[2] = {};
#pragma unroll
  for (int s = 0; s < 12; ++s) {
    const int k0 = s * 32;
    f16x8 a0 = *(const f16x8*)(Ahi + fr * 392 + k0 + qk);
    f16x8 a1 = *(const f16x8*)(Ahi + (16 + fr) * 392 + k0 + qk);
    acc[0] = __builtin_amdgcn_mfma_f32_16x16x32_f16(a0, wf[s], acc[0], 0, 0, 0);
    acc[1] = __builtin_amdgcn_mfma_f32_16x16x32_f16(a1, wf[s], acc[1], 0, 0, 0);
  }
  const int quad = lane >> 4;
  const int og = ob + fr;
  float bias = 0.f;
#pragma unroll
  for (int e = 0; e < 10; ++e) bias += en[e] * bpool[e * 64 + og];
#pragma unroll
  for (int i2 = 0; i2 < 2; ++i2)
#pragma unroll
    for (int r = 0; r < 4; ++r) {
      const int b = i2 * 16 + quad * 4 + r;
      float hc = tanhf(acc[i2][r] + bias);
      float rr = (float)rb[(long)n * 2048 + b * 64 + og];
      float xv = x[(long)b * 131072 + (long)n * 64 + og];
      out[(long)b * 131072 + (long)n * 64 + og] = rr * xv + (1.0f - rr) * hc;
    }
}

extern "C" void kernel_launch(void* const* d_in, const int* in_sizes, int n_in,
                              void* d_out, int out_size, void* d_ws, size_t ws_size,
                              hipStream_t stream) {
  (void)in_sizes; (void)n_in; (void)out_size;
  const float* x   = (const float*)d_in[0];
  const float* emb = (const float*)d_in[2];
  const float* gwp = (const float*)d_in[3];
  const float* gbp = (const float*)d_in[4];
  const float* uwp = (const float*)d_in[5];
  const float* ubp = (const float*)d_in[6];
  float* out = (float*)d_out;
  char* ws = (char*)d_ws;

  // high-water 169,738,240 B.
  if (ws_size < 169738240ull) return;

  // Phases: P0 setup | P1 G1,G2 | P2 gate | P3 tsplit,G3,G4 | P4 wgen(Wu),update
  f16_t*  Xg1h  = (f16_t*)(ws);                  //  8 MiB  (P1..P4)
  f16_t*  Xg2h  = (f16_t*)(ws + 8388608);        //  8 MiB  (P1..P4)
  f16_t*  Zh    = (f16_t*)(ws + 16777216);       //  8 MiB  (P2..P4)
  f16_t*  T1h   = (f16_t*)(ws + 16777216);       //  8 MiB overlay (P1 only: G1->G2)
  f16_t*  rb    = (f16_t*)(ws + 25165824);       //  8 MiB  (P2..P4)
  float*  Pg    = (float*)(ws + 33554432);       // 983040
  float*  Pu    = (float*)(ws + 34537472);       // 983040 (ends 35520512)
  f16_t*  adjF  = (f16_t*)(ws + 35520512);       //  8 MiB  (P0..P3)
  f16_t*  Sh    = (f16_t*)(ws + 43909120);       //  8 MiB  (P1, P3)
  f16_t*  Wg    = (f16_t*)(ws + 52297728);       // 96 MiB  (dead post-gate; ends 152961024)
  f16_t*  T2h   = (f16_t*)(ws + 52297728);       //  8 MiB overlay Wg head (P3)
  f16_t*  Wu    = (f16_t*)(ws + 52297728);       // 96 MiB overlay (P4)
  f16_t*  Cgz1h = (f16_t*)(ws + 152961024);      //  8 MiB  (P3..P4)
  f16_t*  Cgz2h = (f16_t*)(ws + 161349632);      //  8 MiB  (ends 169738240)

  permute_pool<<<960, 256, 0, stream>>>(gwp, Pg, 192, 64, 128);
  permute_pool<<<960, 256, 0, stream>>>(uwp, Pu, 384, 128, 64);
  wgen<<<dim3(12, 128), 256, 0, stream>>>(Pg, emb, Wg);
  adj_softmax<<<2048, 256, 0, stream>>>(emb, adjF);
  split_xt<<<dim3(32, 32), 256, 0, stream>>>(x, Sh);

  // G1: Xg1 = adj @ X     (+ fused transposed fp16 C -> T1)
  fgemm<1><<<dim3(32, 16), 256, 0, stream>>>(adjF, Sh, Xg1h, T1h, 2048, 2048);
  // G2: Xg2 = adj @ Xg1
  fgemm<0><<<dim3(32, 16), 256, 0, stream>>>(adjF, T1h, Xg2h, nullptr, 2048, 2048);

  gate_kernel<<<2048, 256, 0, stream>>>(x, Xg1h, Xg2h, Wg, gbp, emb, Zh, rb);

  tsplit<<<dim3(32, 32), 256, 0, stream>>>(Zh, Sh, 2048, 2048);
  // G3: Cgz1 = adj @ Z    (+ fused transposed fp16 C -> T2, in dead-Wg space)
  fgemm<1><<<dim3(32, 16), 256, 0, stream>>>(adjF, Sh, Cgz1h, T2h, 2048, 2048);
  // G4: Cgz2 = adj @ Cgz1
  fgemm<0><<<dim3(32, 16), 256, 0, stream>>>(adjF, T2h, Cgz2h, nullptr, 2048, 2048);

  wgen<<<dim3(12, 128), 256, 0, stream>>>(Pu, emb, Wu);
  update_kernel<<<2048, 256, 0, stream>>>(x, Zh, Xg1h, Cgz1h, Xg2h, Cgz2h, Wu,
                                          ubp, emb, rb, out);
}